// Round 1
// baseline (684.164 us; speedup 1.0000x reference)
//
#include <hip/hip_runtime.h>
#include <hip/hip_bf16.h>

#define NPIX 8192
#define BATCH 8
#define CCH 128
#define CEMB 64
#define NG 26               // channel groups: 5 payload + 1 norm channel each
#define LS_STRIDE (NPIX + 8)

__device__ __forceinline__ unsigned short f2b(float f) {
    unsigned int u = __float_as_uint(f);
    u = (u + 0x7FFFu + ((u >> 16) & 1u)) >> 16;
    return (unsigned short)u;
}
__device__ __forceinline__ float b2f(unsigned short h) {
    return __uint_as_float(((unsigned int)h) << 16);
}
__device__ __forceinline__ float lo16(unsigned int w) { return __uint_as_float(w << 16); }
__device__ __forceinline__ float hi16(unsigned int w) { return __uint_as_float(w & 0xFFFF0000u); }
__device__ __forceinline__ unsigned int pack2(float lo, float hi) {
    return ((unsigned int)f2b(hi) << 16) | (unsigned int)f2b(lo);
}

// ---------------------------------------------------------------------------
// Prep: per batch, compute inverse BFS order, node depth (pointer jumping),
// level boundaries (BFS order is depth-sorted), child ranges (parent_pos is
// sorted non-decreasing -> binary search).
// ---------------------------------------------------------------------------
__global__ void __launch_bounds__(1024) k_prep(
    const int* __restrict__ bfs_order,
    const int* __restrict__ bfs_parent,
    unsigned short* __restrict__ child_info,
    int* __restrict__ level_starts,
    int* __restrict__ nlevels,
    unsigned short* __restrict__ inv_u16)
{
    const int b = blockIdx.x;
    const int tid = threadIdx.x;
    const int T = blockDim.x;
    __shared__ unsigned short pp[NPIX];
    __shared__ unsigned short pA[NPIX], pB[NPIX], dA[NPIX], dB[NPIX];
    const int* par = bfs_parent + (size_t)b * NPIX;
    const int* ord = bfs_order + (size_t)b * NPIX;
    for (int k = tid; k < NPIX; k += T) {
        int p = par[k];
        pp[k] = (unsigned short)p;
        pA[k] = (unsigned short)p;
        dA[k] = (k == 0) ? 0 : 1;
        inv_u16[(size_t)b * NPIX + ord[k]] = (unsigned short)k;
    }
    __syncthreads();
    unsigned short *pc = pA, *pn = pB, *dc = dA, *dn = dB;
    for (int r = 0; r < 13; r++) {
        for (int k = tid; k < NPIX; k += T) {
            int p = pc[k];
            dn[k] = (unsigned short)(dc[k] + dc[p]);
            pn[k] = pc[p];
        }
        __syncthreads();
        unsigned short* t;
        t = pc; pc = pn; pn = t;
        t = dc; dc = dn; dn = t;
    }
    // child ranges: children of k = contiguous run of parent_pos == k, j in [1,N)
    for (int k = tid; k < NPIX; k += T) {
        int lo = 1, hi = NPIX;
        while (lo < hi) { int m = (lo + hi) >> 1; if ((int)pp[m] < k) lo = m + 1; else hi = m; }
        int cs = lo;
        hi = NPIX;
        while (lo < hi) { int m = (lo + hi) >> 1; if ((int)pp[m] < k + 1) lo = m + 1; else hi = m; }
        int cnt = lo - cs;
        if (cnt <= 0) { cs = 0; cnt = 0; }
        child_info[(size_t)b * NPIX + k] = (unsigned short)((cs << 3) | cnt);
    }
    // level starts: depth is non-decreasing, steps by exactly +1 at boundaries
    int* LS = level_starts + (size_t)b * LS_STRIDE;
    for (int k = tid; k < NPIX; k += T) {
        if (k == 0) LS[0] = 0;
        else if (dc[k] != dc[k - 1]) LS[(int)dc[k]] = k;
    }
    if (tid == 0) {
        int nl = (int)dc[NPIX - 1] + 1;
        nlevels[b] = nl;
        LS[nl] = NPIX;
    }
}

// ---------------------------------------------------------------------------
// Embed: e[b][pix][ce] = sum_c W_embed[ce][c] * last_fm[b][c][pix]  (f32)
// ---------------------------------------------------------------------------
__global__ void __launch_bounds__(256) k_embed(
    const float* __restrict__ last_fm,
    const float* __restrict__ W_embed,
    float* __restrict__ e)
{
    __shared__ float Ws[CEMB * CCH];
    const int tid = threadIdx.x;
    for (int i = tid; i < CEMB * CCH; i += 256) Ws[i] = W_embed[i];
    __syncthreads();
    const int b = blockIdx.y;
    const int pix = blockIdx.x * 256 + tid;
    float acc[CEMB];
#pragma unroll
    for (int i = 0; i < CEMB; i++) acc[i] = 0.f;
    for (int cc = 0; cc < CCH; cc += 8) {
        float x[8];
#pragma unroll
        for (int j = 0; j < 8; j++) x[j] = last_fm[((size_t)(b * CCH + cc + j)) * NPIX + pix];
#pragma unroll
        for (int ce = 0; ce < CEMB; ce++) {
            const float4 wa = *(const float4*)&Ws[ce * CCH + cc];
            const float4 wb = *(const float4*)&Ws[ce * CCH + cc + 4];
            acc[ce] += wa.x * x[0] + wa.y * x[1] + wa.z * x[2] + wa.w * x[3]
                     + wb.x * x[4] + wb.y * x[5] + wb.z * x[6] + wb.w * x[7];
        }
    }
    float4* ep = (float4*)&e[((size_t)b * NPIX + pix) * CEMB];
#pragma unroll
    for (int q = 0; q < 16; q++)
        ep[q] = make_float4(acc[4 * q], acc[4 * q + 1], acc[4 * q + 2], acc[4 * q + 3]);
}

// ---------------------------------------------------------------------------
// Edge weights: w[b][k] = exp(-||e[order[k]] - e[order[parent[k]]]||^2)
// one wave per node, lane = embed channel
// ---------------------------------------------------------------------------
__global__ void __launch_bounds__(256) k_w(
    const float* __restrict__ e,
    const int* __restrict__ bfs_order,
    const int* __restrict__ bfs_parent,
    float* __restrict__ wout)
{
    const int lane = threadIdx.x & 63;
    const int wv = threadIdx.x >> 6;
    const int b = blockIdx.y;
    const int k = blockIdx.x * 4 + wv;
    const int u = bfs_order[(size_t)b * NPIX + k];
    const int p = bfs_parent[(size_t)b * NPIX + k];
    const int v = bfs_order[(size_t)b * NPIX + p];
    float du = e[((size_t)b * NPIX + u) * CEMB + lane] - e[((size_t)b * NPIX + v) * CEMB + lane];
    float s = du * du;
#pragma unroll
    for (int off = 32; off > 0; off >>= 1) s += __shfl_xor(s, off);
    if (lane == 0) wout[(size_t)b * NPIX + k] = expf(-s);
}

// ---------------------------------------------------------------------------
// Tree scan: per block = (batch, channel-group of 5 payload + 1 norm).
// A rows (6 x bf16 = 3 u32) live entirely in LDS. Level-synchronous up
// (parent gathers children, no atomics) then down, then fused
// fusion = latent + Y/Ynorm written coalesced in pixel order.
// ---------------------------------------------------------------------------
__global__ void __launch_bounds__(64) k_scan(
    const float* __restrict__ last_fm,
    const float* __restrict__ latent,
    const float* __restrict__ wglob,
    const unsigned short* __restrict__ inv_u16,
    const unsigned short* __restrict__ child_info,
    const int* __restrict__ bfs_parent,
    const int* __restrict__ level_starts,
    const int* __restrict__ nlevels,
    float* __restrict__ fusion)
{
    __shared__ unsigned int A32[NPIX * 3];       // 96KB: rows of 6 bf16
    __shared__ unsigned short wL[NPIX];          // 16KB
    __shared__ unsigned short meta[NPIX];        // 16KB (inv -> chi -> par -> inv)
    __shared__ unsigned short LSs[NPIX + 8];     // 16.4KB level starts

    const int b = blockIdx.x / NG, g = blockIdx.x % NG;
    const int lane = threadIdx.x;
    const size_t base = (size_t)b * NPIX;
    const int nl = nlevels[b];
    const int c0 = g * 5;

    for (int k = lane; k < NPIX; k += 64) wL[k] = f2b(wglob[base + k]);
    for (int l = lane; l <= nl; l += 64) LSs[l] = (unsigned short)level_starts[(size_t)b * LS_STRIDE + l];
    for (int k = lane; k < NPIX; k += 64) meta[k] = inv_u16[base + k];
    __syncthreads();

    // init A: coalesced channel-plane reads, scattered LDS writes via inv
    for (int pix = lane; pix < NPIX; pix += 64) {
        const int n = meta[pix];
        float v0 = (c0 + 0 < CCH) ? last_fm[((size_t)(b * CCH + c0 + 0)) * NPIX + pix] : 0.f;
        float v1 = (c0 + 1 < CCH) ? last_fm[((size_t)(b * CCH + c0 + 1)) * NPIX + pix] : 0.f;
        float v2 = (c0 + 2 < CCH) ? last_fm[((size_t)(b * CCH + c0 + 2)) * NPIX + pix] : 0.f;
        float v3 = (c0 + 3 < CCH) ? last_fm[((size_t)(b * CCH + c0 + 3)) * NPIX + pix] : 0.f;
        float v4 = (c0 + 4 < CCH) ? last_fm[((size_t)(b * CCH + c0 + 4)) * NPIX + pix] : 0.f;
        A32[n * 3 + 0] = pack2(v0, v1);
        A32[n * 3 + 1] = pack2(v2, v3);
        A32[n * 3 + 2] = ((unsigned int)0x3F80u << 16) | (unsigned int)f2b(v4);  // norm=1.0
    }
    __syncthreads();
    for (int k = lane; k < NPIX; k += 64) meta[k] = child_info[base + k];
    __syncthreads();

    // UP: A[k] += sum_children w_j * A[j]; levels deepest -> root
    for (int l = nl - 1; l >= 0; --l) {
        const int s = LSs[l], epos = LSs[l + 1];
        for (int k = s + lane; k < epos; k += 64) {
            const int ci = meta[k];
            const int cnt = ci & 7;
            if (cnt) {
                const int cs = ci >> 3;
                unsigned int r0 = A32[k * 3], r1 = A32[k * 3 + 1], r2 = A32[k * 3 + 2];
                float a0 = lo16(r0), a1 = hi16(r0), a2 = lo16(r1), a3 = hi16(r1), a4 = lo16(r2), a5 = hi16(r2);
                for (int t = 0; t < cnt; t++) {
                    const int j = cs + t;
                    const float wj = b2f(wL[j]);
                    unsigned int u0 = A32[j * 3], u1 = A32[j * 3 + 1], u2 = A32[j * 3 + 2];
                    a0 += wj * lo16(u0); a1 += wj * hi16(u0);
                    a2 += wj * lo16(u1); a3 += wj * hi16(u1);
                    a4 += wj * lo16(u2); a5 += wj * hi16(u2);
                }
                A32[k * 3 + 0] = pack2(a0, a1);
                A32[k * 3 + 1] = pack2(a2, a3);
                A32[k * 3 + 2] = pack2(a4, a5);
            }
        }
        __syncthreads();
    }

    for (int k = lane; k < NPIX; k += 64) meta[k] = (unsigned short)bfs_parent[base + k];
    __syncthreads();

    // DOWN: Y[k] = (1-w^2) A[k] + w * Y[parent]; levels root -> deepest, in place
    for (int l = 1; l < nl; ++l) {
        const int s = LSs[l], epos = LSs[l + 1];
        for (int k = s + lane; k < epos; k += 64) {
            const float wk = b2f(wL[k]);
            const int p = meta[k];
            unsigned int r0 = A32[k * 3], r1 = A32[k * 3 + 1], r2 = A32[k * 3 + 2];
            unsigned int q0 = A32[p * 3], q1 = A32[p * 3 + 1], q2 = A32[p * 3 + 2];
            const float om = 1.f - wk * wk;
            float y0 = om * lo16(r0) + wk * lo16(q0);
            float y1 = om * hi16(r0) + wk * hi16(q0);
            float y2 = om * lo16(r1) + wk * lo16(q1);
            float y3 = om * hi16(r1) + wk * hi16(q1);
            float y4 = om * lo16(r2) + wk * lo16(q2);
            float y5 = om * hi16(r2) + wk * hi16(q2);
            A32[k * 3 + 0] = pack2(y0, y1);
            A32[k * 3 + 1] = pack2(y2, y3);
            A32[k * 3 + 2] = pack2(y4, y5);
        }
        __syncthreads();
    }

    for (int k = lane; k < NPIX; k += 64) meta[k] = inv_u16[base + k];
    __syncthreads();

    // writeback: fusion = latent + Y/Ynorm, coalesced in pixel order
    for (int pix = lane; pix < NPIX; pix += 64) {
        const int n = meta[pix];
        unsigned int r0 = A32[n * 3], r1 = A32[n * 3 + 1], r2 = A32[n * 3 + 2];
        const float rn = 1.f / hi16(r2);
        float y0 = lo16(r0) * rn, y1 = hi16(r0) * rn, y2 = lo16(r1) * rn, y3 = hi16(r1) * rn, y4 = lo16(r2) * rn;
        if (c0 + 0 < CCH) fusion[((size_t)(b * CCH + c0 + 0)) * NPIX + pix] = latent[((size_t)(b * CCH + c0 + 0)) * NPIX + pix] + y0;
        if (c0 + 1 < CCH) fusion[((size_t)(b * CCH + c0 + 1)) * NPIX + pix] = latent[((size_t)(b * CCH + c0 + 1)) * NPIX + pix] + y1;
        if (c0 + 2 < CCH) fusion[((size_t)(b * CCH + c0 + 2)) * NPIX + pix] = latent[((size_t)(b * CCH + c0 + 2)) * NPIX + pix] + y2;
        if (c0 + 3 < CCH) fusion[((size_t)(b * CCH + c0 + 3)) * NPIX + pix] = latent[((size_t)(b * CCH + c0 + 3)) * NPIX + pix] + y3;
        if (c0 + 4 < CCH) fusion[((size_t)(b * CCH + c0 + 4)) * NPIX + pix] = latent[((size_t)(b * CCH + c0 + 4)) * NPIX + pix] + y4;
    }
}

// ---------------------------------------------------------------------------
// Refine: out[b][o][pix] = sum_c W_refine[o][c] * fusion[b][c][pix]
// o split in halves via blockIdx.z; 2 pixels per thread.
// ---------------------------------------------------------------------------
__global__ void __launch_bounds__(256) k_refine(
    const float* __restrict__ fusion,
    const float* __restrict__ W_refine,
    float* __restrict__ out)
{
    __shared__ float Ws[64 * CCH];
    const int tid = threadIdx.x;
    const int half = blockIdx.z;
    for (int i = tid; i < 64 * CCH; i += 256) Ws[i] = W_refine[(size_t)half * 64 * CCH + i];
    __syncthreads();
    const int b = blockIdx.y;
    const int pix0 = blockIdx.x * 512 + tid;
    const int pix1 = pix0 + 256;
    float acc0[64], acc1[64];
#pragma unroll
    for (int i = 0; i < 64; i++) { acc0[i] = 0.f; acc1[i] = 0.f; }
    for (int cc = 0; cc < CCH; cc += 8) {
        float x0[8], x1[8];
#pragma unroll
        for (int j = 0; j < 8; j++) {
            const size_t rb = ((size_t)(b * CCH + cc + j)) * NPIX;
            x0[j] = fusion[rb + pix0];
            x1[j] = fusion[rb + pix1];
        }
#pragma unroll
        for (int o = 0; o < 64; o++) {
            const float4 wa = *(const float4*)&Ws[o * CCH + cc];
            const float4 wb = *(const float4*)&Ws[o * CCH + cc + 4];
            acc0[o] += wa.x * x0[0] + wa.y * x0[1] + wa.z * x0[2] + wa.w * x0[3]
                     + wb.x * x0[4] + wb.y * x0[5] + wb.z * x0[6] + wb.w * x0[7];
            acc1[o] += wa.x * x1[0] + wa.y * x1[1] + wa.z * x1[2] + wa.w * x1[3]
                     + wb.x * x1[4] + wb.y * x1[5] + wb.z * x1[6] + wb.w * x1[7];
        }
    }
#pragma unroll
    for (int o = 0; o < 64; o++) {
        const size_t rb = ((size_t)(b * CCH + half * 64 + o)) * NPIX;
        out[rb + pix0] = acc0[o];
        out[rb + pix1] = acc1[o];
    }
}

extern "C" void kernel_launch(void* const* d_in, const int* in_sizes, int n_in,
                              void* d_out, int out_size, void* d_ws, size_t ws_size,
                              hipStream_t stream)
{
    const float* latent   = (const float*)d_in[0];
    const float* last_fm  = (const float*)d_in[1];
    const float* W_embed  = (const float*)d_in[2];
    const float* W_refine = (const float*)d_in[3];
    const int* bfs_order  = (const int*)d_in[4];
    const int* bfs_parent = (const int*)d_in[5];
    float* out = (float*)d_out;

    char* ws = (char*)d_ws;
    size_t off = 0;
    auto alloc = [&](size_t bytes) -> char* {
        char* p = ws + off;
        off = (off + bytes + 255) & ~(size_t)255;
        return p;
    };
    float* e = (float*)alloc((size_t)BATCH * NPIX * CEMB * 4);          // 16.8 MB
    float* wbuf = (float*)alloc((size_t)BATCH * NPIX * 4);              // 256 KB
    unsigned short* chi = (unsigned short*)alloc((size_t)BATCH * NPIX * 2);
    unsigned short* inv = (unsigned short*)alloc((size_t)BATCH * NPIX * 2);
    int* LS = (int*)alloc((size_t)BATCH * LS_STRIDE * 4);
    int* nl = (int*)alloc((size_t)BATCH * 4);
    float* fusion = (float*)alloc((size_t)BATCH * CCH * NPIX * 4);      // 33.6 MB

    k_prep<<<dim3(BATCH), dim3(1024), 0, stream>>>(bfs_order, bfs_parent, chi, LS, nl, inv);
    k_embed<<<dim3(NPIX / 256, BATCH), dim3(256), 0, stream>>>(last_fm, W_embed, e);
    k_w<<<dim3(NPIX / 4, BATCH), dim3(256), 0, stream>>>(e, bfs_order, bfs_parent, wbuf);
    k_scan<<<dim3(BATCH * NG), dim3(64), 0, stream>>>(last_fm, latent, wbuf, inv, chi,
                                                      bfs_parent, LS, nl, fusion);
    k_refine<<<dim3(NPIX / 512, BATCH, 2), dim3(256), 0, stream>>>(fusion, W_refine, out);
}

// Round 2
// 631.635 us; speedup vs baseline: 1.0832x; 1.0832x over previous
//
#include <hip/hip_runtime.h>
#include <hip/hip_bf16.h>

#define NPIX 8192
#define BATCH 8
#define CCH 128
#define CEMB 64
#define NG 26               // channel groups: 5 payload + 1 norm channel each
#define LS_STRIDE (NPIX + 8)
#define MAXLVL 6144

__device__ __forceinline__ float lo16(unsigned int w) { return __uint_as_float(w << 16); }
__device__ __forceinline__ float hi16(unsigned int w) { return __uint_as_float(w & 0xFFFF0000u); }
__device__ __forceinline__ unsigned int cvtpk(float lo, float hi) {
    unsigned int r;
    asm("v_cvt_pk_bf16_f32 %0, %1, %2" : "=v"(r) : "v"(lo), "v"(hi));
    return r;
}

// ---------------------------------------------------------------------------
// Prep: per batch, compute inverse BFS order, node depth (pointer jumping),
// level boundaries (BFS order is depth-sorted), child ranges (parent_pos is
// sorted non-decreasing -> binary search).
// ---------------------------------------------------------------------------
__global__ void __launch_bounds__(1024) k_prep(
    const int* __restrict__ bfs_order,
    const int* __restrict__ bfs_parent,
    unsigned short* __restrict__ child_info,
    int* __restrict__ level_starts,
    int* __restrict__ nlevels,
    unsigned short* __restrict__ inv_u16)
{
    const int b = blockIdx.x;
    const int tid = threadIdx.x;
    const int T = blockDim.x;
    __shared__ unsigned short pp[NPIX];
    __shared__ unsigned short pA[NPIX], pB[NPIX], dA[NPIX], dB[NPIX];
    const int* par = bfs_parent + (size_t)b * NPIX;
    const int* ord = bfs_order + (size_t)b * NPIX;
    for (int k = tid; k < NPIX; k += T) {
        int p = par[k];
        pp[k] = (unsigned short)p;
        pA[k] = (unsigned short)p;
        dA[k] = (k == 0) ? 0 : 1;
        inv_u16[(size_t)b * NPIX + ord[k]] = (unsigned short)k;
    }
    __syncthreads();
    unsigned short *pc = pA, *pn = pB, *dc = dA, *dn = dB;
    for (int r = 0; r < 13; r++) {
        for (int k = tid; k < NPIX; k += T) {
            int p = pc[k];
            dn[k] = (unsigned short)(dc[k] + dc[p]);
            pn[k] = pc[p];
        }
        __syncthreads();
        unsigned short* t;
        t = pc; pc = pn; pn = t;
        t = dc; dc = dn; dn = t;
    }
    for (int k = tid; k < NPIX; k += T) {
        int lo = 1, hi = NPIX;
        while (lo < hi) { int m = (lo + hi) >> 1; if ((int)pp[m] < k) lo = m + 1; else hi = m; }
        int cs = lo;
        hi = NPIX;
        while (lo < hi) { int m = (lo + hi) >> 1; if ((int)pp[m] < k + 1) lo = m + 1; else hi = m; }
        int cnt = lo - cs;
        if (cnt <= 0) { cs = 0; cnt = 0; }
        child_info[(size_t)b * NPIX + k] = (unsigned short)((cs << 3) | cnt);
    }
    int* LS = level_starts + (size_t)b * LS_STRIDE;
    for (int k = tid; k < NPIX; k += T) {
        if (k == 0) LS[0] = 0;
        else if (dc[k] != dc[k - 1]) LS[(int)dc[k]] = k;
    }
    if (tid == 0) {
        int nl = (int)dc[NPIX - 1] + 1;
        nlevels[b] = nl;
        LS[nl] = NPIX;
    }
}

// ---------------------------------------------------------------------------
// Embed: e[b][pix][ce] = sum_c W_embed[ce][c] * last_fm[b][c][pix]  (f32)
// ---------------------------------------------------------------------------
__global__ void __launch_bounds__(256) k_embed(
    const float* __restrict__ last_fm,
    const float* __restrict__ W_embed,
    float* __restrict__ e)
{
    __shared__ float Ws[CEMB * CCH];
    const int tid = threadIdx.x;
    for (int i = tid; i < CEMB * CCH; i += 256) Ws[i] = W_embed[i];
    __syncthreads();
    const int b = blockIdx.y;
    const int pix = blockIdx.x * 256 + tid;
    float acc[CEMB];
#pragma unroll
    for (int i = 0; i < CEMB; i++) acc[i] = 0.f;
    for (int cc = 0; cc < CCH; cc += 8) {
        float x[8];
#pragma unroll
        for (int j = 0; j < 8; j++) x[j] = last_fm[((size_t)(b * CCH + cc + j)) * NPIX + pix];
#pragma unroll
        for (int ce = 0; ce < CEMB; ce++) {
            const float4 wa = *(const float4*)&Ws[ce * CCH + cc];
            const float4 wb = *(const float4*)&Ws[ce * CCH + cc + 4];
            acc[ce] += wa.x * x[0] + wa.y * x[1] + wa.z * x[2] + wa.w * x[3]
                     + wb.x * x[4] + wb.y * x[5] + wb.z * x[6] + wb.w * x[7];
        }
    }
    float4* ep = (float4*)&e[((size_t)b * NPIX + pix) * CEMB];
#pragma unroll
    for (int q = 0; q < 16; q++)
        ep[q] = make_float4(acc[4 * q], acc[4 * q + 1], acc[4 * q + 2], acc[4 * q + 3]);
}

// ---------------------------------------------------------------------------
// Edge weights: w[b][k] = exp(-||e[order[k]] - e[order[parent[k]]]||^2)
// ---------------------------------------------------------------------------
__global__ void __launch_bounds__(256) k_w(
    const float* __restrict__ e,
    const int* __restrict__ bfs_order,
    const int* __restrict__ bfs_parent,
    float* __restrict__ wout)
{
    const int lane = threadIdx.x & 63;
    const int wv = threadIdx.x >> 6;
    const int b = blockIdx.y;
    const int k = blockIdx.x * 4 + wv;
    const int u = bfs_order[(size_t)b * NPIX + k];
    const int p = bfs_parent[(size_t)b * NPIX + k];
    const int v = bfs_order[(size_t)b * NPIX + p];
    float du = e[((size_t)b * NPIX + u) * CEMB + lane] - e[((size_t)b * NPIX + v) * CEMB + lane];
    float s = du * du;
#pragma unroll
    for (int off = 32; off > 0; off >>= 1) s += __shfl_xor(s, off);
    if (lane == 0) wout[(size_t)b * NPIX + k] = expf(-s);
}

// ---------------------------------------------------------------------------
// Tree scan, round 2: 16B rows [pk(c0,c1), pk(c2,c3), pk(c4,norm), w_f32].
// One ds_read_b128 per child; child loop unrolled to 4 (grid MST => cnt<=4);
// next level's bounds/meta/own-row prefetched one level ahead so the only
// dependent LDS access per level is the child (up) / parent (down) row.
// ---------------------------------------------------------------------------
__device__ __forceinline__ void up_node(uint4* As, int k, int m, uint4 r) {
    const int cnt = m & 7, cs = m >> 3;
    float a0 = lo16(r.x), a1 = hi16(r.x), a2 = lo16(r.y), a3 = hi16(r.y),
          a4 = lo16(r.z), a5 = hi16(r.z);
#pragma unroll
    for (int t = 0; t < 4; t++) {
        int j = cs + t;
        j = j < NPIX ? j : NPIX - 1;
        const uint4 c = As[j];
        const float wj = (t < cnt) ? __uint_as_float(c.w) : 0.f;
        a0 = fmaf(wj, lo16(c.x), a0); a1 = fmaf(wj, hi16(c.x), a1);
        a2 = fmaf(wj, lo16(c.y), a2); a3 = fmaf(wj, hi16(c.y), a3);
        a4 = fmaf(wj, lo16(c.z), a4); a5 = fmaf(wj, hi16(c.z), a5);
    }
    As[k] = make_uint4(cvtpk(a0, a1), cvtpk(a2, a3), cvtpk(a4, a5), r.w);
}

__device__ __forceinline__ void down_node(uint4* As, int k, int p, uint4 r) {
    const float w = __uint_as_float(r.w);
    const uint4 q = As[p];
    const float a0 = lo16(r.x), a1 = hi16(r.x), a2 = lo16(r.y), a3 = hi16(r.y),
                a4 = lo16(r.z), a5 = hi16(r.z);
    const float y0 = fmaf(w, fmaf(-w, a0, lo16(q.x)), a0);
    const float y1 = fmaf(w, fmaf(-w, a1, hi16(q.x)), a1);
    const float y2 = fmaf(w, fmaf(-w, a2, lo16(q.y)), a2);
    const float y3 = fmaf(w, fmaf(-w, a3, hi16(q.y)), a3);
    const float y4 = fmaf(w, fmaf(-w, a4, lo16(q.z)), a4);
    const float y5 = fmaf(w, fmaf(-w, a5, hi16(q.z)), a5);
    As[k] = make_uint4(cvtpk(y0, y1), cvtpk(y2, y3), cvtpk(y4, y5), r.w);
}

__global__ void __launch_bounds__(64) k_scan(
    const float* __restrict__ last_fm,
    const float* __restrict__ latent,
    const float* __restrict__ wglob,
    const unsigned short* __restrict__ inv_u16,
    const unsigned short* __restrict__ child_info,
    const int* __restrict__ bfs_parent,
    const int* __restrict__ level_starts,
    const int* __restrict__ nlevels,
    float* __restrict__ fusion)
{
    __shared__ uint4 As[NPIX];                   // 128KB
    __shared__ unsigned short meta[NPIX];        // 16KB
    __shared__ unsigned short LSs[MAXLVL];       // 12KB

    const int b = blockIdx.x / NG, g = blockIdx.x % NG;
    const int lane = threadIdx.x;
    const size_t base = (size_t)b * NPIX;
    const int nl = nlevels[b];
    const int c0 = g * 5;

    for (int l = lane; l <= nl; l += 64) LSs[l] = (unsigned short)level_starts[(size_t)b * LS_STRIDE + l];
    for (int k = lane; k < NPIX; k += 64) meta[k] = inv_u16[base + k];
    __syncthreads();

    // init rows: coalesced channel-plane reads, scattered LDS b128 writes
    for (int pix = lane; pix < NPIX; pix += 64) {
        const int n = meta[pix];
        float v0 = (c0 + 0 < CCH) ? last_fm[((size_t)(b * CCH + c0 + 0)) * NPIX + pix] : 0.f;
        float v1 = (c0 + 1 < CCH) ? last_fm[((size_t)(b * CCH + c0 + 1)) * NPIX + pix] : 0.f;
        float v2 = (c0 + 2 < CCH) ? last_fm[((size_t)(b * CCH + c0 + 2)) * NPIX + pix] : 0.f;
        float v3 = (c0 + 3 < CCH) ? last_fm[((size_t)(b * CCH + c0 + 3)) * NPIX + pix] : 0.f;
        float v4 = (c0 + 4 < CCH) ? last_fm[((size_t)(b * CCH + c0 + 4)) * NPIX + pix] : 0.f;
        As[n] = make_uint4(cvtpk(v0, v1), cvtpk(v2, v3), cvtpk(v4, 1.0f), 0u);
    }
    __syncthreads();
    {   // edge weight (f32) into slot 3, coalesced global read
        unsigned int* a32 = (unsigned int*)As;
        for (int k = lane; k < NPIX; k += 64) a32[k * 4 + 3] = __float_as_uint(wglob[base + k]);
    }
    for (int k = lane; k < NPIX; k += 64) meta[k] = child_info[base + k];
    __syncthreads();

    // ---- UP sweep (deepest -> root), pipelined one level ahead ----
    {
        int l = nl - 1;
        int sC = LSs[l], eC = NPIX;
        int kC = sC + lane;
        bool aC = kC < eC;
        int kCc = aC ? kC : 0;
        int mC = meta[kCc];
        uint4 rC = As[kCc];
        for (; l >= 0; --l) {
            const int sN = (l > 0) ? (int)LSs[l - 1] : 0;
            const int eN = sC;
            const int kN = sN + lane;
            const bool aN = (l > 0) && (kN < eN);
            const int kNc = aN ? kN : 0;
            const int mN = meta[kNc];
            const uint4 rN = As[kNc];
            if (aC) up_node(As, kC, mC, rC);
            for (int k = kC + 64; k < eC; k += 64) up_node(As, k, meta[k], As[k]);
            __syncthreads();
            sC = sN; eC = eN; kC = kN; aC = aN; mC = mN; rC = rN;
        }
    }

    for (int k = lane; k < NPIX; k += 64) meta[k] = (unsigned short)bfs_parent[base + k];
    __syncthreads();

    // ---- DOWN sweep (root -> deepest), pipelined one level ahead ----
    if (nl >= 2) {
        int l = 1;
        int sC = LSs[1], eC = LSs[2];
        int kC = sC + lane;
        bool aC = kC < eC;
        int kCc = aC ? kC : 0;
        int mC = meta[kCc];
        uint4 rC = As[kCc];
        for (; l < nl; ++l) {
            const int sN = eC;
            const int eN = (l + 2 <= nl) ? (int)LSs[l + 2] : sN;
            const int kN = sN + lane;
            const bool aN = (l + 1 < nl) && (kN < eN);
            const int kNc = aN ? kN : 0;
            const int mN = meta[kNc];
            const uint4 rN = As[kNc];
            if (aC) down_node(As, kC, mC, rC);
            for (int k = kC + 64; k < eC; k += 64) down_node(As, k, meta[k], As[k]);
            __syncthreads();
            sC = sN; eC = eN; kC = kN; aC = aN; mC = mN; rC = rN;
        }
    }

    for (int k = lane; k < NPIX; k += 64) meta[k] = inv_u16[base + k];
    __syncthreads();

    // writeback: fusion = latent + Y/Ynorm, coalesced in pixel order
    for (int pix = lane; pix < NPIX; pix += 64) {
        const int n = meta[pix];
        const uint4 r = As[n];
        const float rn = 1.f / hi16(r.z);
        const float y0 = lo16(r.x) * rn, y1 = hi16(r.x) * rn;
        const float y2 = lo16(r.y) * rn, y3 = hi16(r.y) * rn;
        const float y4 = lo16(r.z) * rn;
        if (c0 + 0 < CCH) fusion[((size_t)(b * CCH + c0 + 0)) * NPIX + pix] = latent[((size_t)(b * CCH + c0 + 0)) * NPIX + pix] + y0;
        if (c0 + 1 < CCH) fusion[((size_t)(b * CCH + c0 + 1)) * NPIX + pix] = latent[((size_t)(b * CCH + c0 + 1)) * NPIX + pix] + y1;
        if (c0 + 2 < CCH) fusion[((size_t)(b * CCH + c0 + 2)) * NPIX + pix] = latent[((size_t)(b * CCH + c0 + 2)) * NPIX + pix] + y2;
        if (c0 + 3 < CCH) fusion[((size_t)(b * CCH + c0 + 3)) * NPIX + pix] = latent[((size_t)(b * CCH + c0 + 3)) * NPIX + pix] + y3;
        if (c0 + 4 < CCH) fusion[((size_t)(b * CCH + c0 + 4)) * NPIX + pix] = latent[((size_t)(b * CCH + c0 + 4)) * NPIX + pix] + y4;
    }
}

// ---------------------------------------------------------------------------
// Refine: out[b][o][pix] = sum_c W_refine[o][c] * fusion[b][c][pix]
// ---------------------------------------------------------------------------
__global__ void __launch_bounds__(256) k_refine(
    const float* __restrict__ fusion,
    const float* __restrict__ W_refine,
    float* __restrict__ out)
{
    __shared__ float Ws[64 * CCH];
    const int tid = threadIdx.x;
    const int half = blockIdx.z;
    for (int i = tid; i < 64 * CCH; i += 256) Ws[i] = W_refine[(size_t)half * 64 * CCH + i];
    __syncthreads();
    const int b = blockIdx.y;
    const int pix0 = blockIdx.x * 512 + tid;
    const int pix1 = pix0 + 256;
    float acc0[64], acc1[64];
#pragma unroll
    for (int i = 0; i < 64; i++) { acc0[i] = 0.f; acc1[i] = 0.f; }
    for (int cc = 0; cc < CCH; cc += 8) {
        float x0[8], x1[8];
#pragma unroll
        for (int j = 0; j < 8; j++) {
            const size_t rb = ((size_t)(b * CCH + cc + j)) * NPIX;
            x0[j] = fusion[rb + pix0];
            x1[j] = fusion[rb + pix1];
        }
#pragma unroll
        for (int o = 0; o < 64; o++) {
            const float4 wa = *(const float4*)&Ws[o * CCH + cc];
            const float4 wb = *(const float4*)&Ws[o * CCH + cc + 4];
            acc0[o] += wa.x * x0[0] + wa.y * x0[1] + wa.z * x0[2] + wa.w * x0[3]
                     + wb.x * x0[4] + wb.y * x0[5] + wb.z * x0[6] + wb.w * x0[7];
            acc1[o] += wa.x * x1[0] + wa.y * x1[1] + wa.z * x1[2] + wa.w * x1[3]
                     + wb.x * x1[4] + wb.y * x1[5] + wb.z * x1[6] + wb.w * x1[7];
        }
    }
#pragma unroll
    for (int o = 0; o < 64; o++) {
        const size_t rb = ((size_t)(b * CCH + half * 64 + o)) * NPIX;
        out[rb + pix0] = acc0[o];
        out[rb + pix1] = acc1[o];
    }
}

extern "C" void kernel_launch(void* const* d_in, const int* in_sizes, int n_in,
                              void* d_out, int out_size, void* d_ws, size_t ws_size,
                              hipStream_t stream)
{
    const float* latent   = (const float*)d_in[0];
    const float* last_fm  = (const float*)d_in[1];
    const float* W_embed  = (const float*)d_in[2];
    const float* W_refine = (const float*)d_in[3];
    const int* bfs_order  = (const int*)d_in[4];
    const int* bfs_parent = (const int*)d_in[5];
    float* out = (float*)d_out;

    char* ws = (char*)d_ws;
    size_t off = 0;
    auto alloc = [&](size_t bytes) -> char* {
        char* p = ws + off;
        off = (off + bytes + 255) & ~(size_t)255;
        return p;
    };
    float* e = (float*)alloc((size_t)BATCH * NPIX * CEMB * 4);
    float* wbuf = (float*)alloc((size_t)BATCH * NPIX * 4);
    unsigned short* chi = (unsigned short*)alloc((size_t)BATCH * NPIX * 2);
    unsigned short* inv = (unsigned short*)alloc((size_t)BATCH * NPIX * 2);
    int* LS = (int*)alloc((size_t)BATCH * LS_STRIDE * 4);
    int* nl = (int*)alloc((size_t)BATCH * 4);
    float* fusion = (float*)alloc((size_t)BATCH * CCH * NPIX * 4);

    k_prep<<<dim3(BATCH), dim3(1024), 0, stream>>>(bfs_order, bfs_parent, chi, LS, nl, inv);
    k_embed<<<dim3(NPIX / 256, BATCH), dim3(256), 0, stream>>>(last_fm, W_embed, e);
    k_w<<<dim3(NPIX / 4, BATCH), dim3(256), 0, stream>>>(e, bfs_order, bfs_parent, wbuf);
    k_scan<<<dim3(BATCH * NG), dim3(64), 0, stream>>>(last_fm, latent, wbuf, inv, chi,
                                                      bfs_parent, LS, nl, fusion);
    k_refine<<<dim3(NPIX / 512, BATCH, 2), dim3(256), 0, stream>>>(fusion, W_refine, out);
}